// Round 3
// baseline (393.408 us; speedup 1.0000x reference)
//
#include <hip/hip_runtime.h>
#include <hip/hip_bf16.h>
#include <math.h>

#define B 256
#define D 1024
#define H 8
#define HD 128
#define P 2048
#define HID 1024
#define EPS 1e-5f

typedef __hip_bfloat16 bf16;
typedef short short8 __attribute__((ext_vector_type(8)));
typedef float f32x4 __attribute__((ext_vector_type(4)));

#define AS1C(p) ((const __attribute__((address_space(1))) void*)(p))
#define AS3(p)  ((__attribute__((address_space(3))) void*)(p))

// ---------------------------------------------------------------------------
// Zero the split-K f32 accumulators. 2359296 floats = 589824 float4.
// ---------------------------------------------------------------------------
__global__ __launch_bounds__(256) void zero_kernel(float* __restrict__ p) {
    const int i = blockIdx.x * 256 + threadIdx.x;
    ((float4*)p)[i] = float4{0.f, 0.f, 0.f, 0.f};
}

// ---------------------------------------------------------------------------
// LayerNorm -> bf16 output
// ---------------------------------------------------------------------------
__global__ __launch_bounds__(256) void ln_kernel(
    const float* __restrict__ seq, const float* __restrict__ w,
    const float* __restrict__ b, bf16* __restrict__ xn)
{
    const int row = blockIdx.x;
    const int tid = threadIdx.x;
    const int lane = tid & 63, wv = tid >> 6;
    const float* x = seq + (size_t)row * D;
    __shared__ float red[8];

    float vals[4];
    float s = 0.f, s2 = 0.f;
#pragma unroll
    for (int i = 0; i < 4; ++i) {
        float v = x[tid + 256 * i];
        vals[i] = v; s += v; s2 += v * v;
    }
#pragma unroll
    for (int off = 32; off; off >>= 1) {
        s  += __shfl_down(s, off, 64);
        s2 += __shfl_down(s2, off, 64);
    }
    if (lane == 0) { red[wv] = s; red[4 + wv] = s2; }
    __syncthreads();
    const float tot  = red[0] + red[1] + red[2] + red[3];
    const float tot2 = red[4] + red[5] + red[6] + red[7];
    const float mu = tot * (1.f / D);
    const float var = tot2 * (1.f / D) - mu * mu;
    const float rs = rsqrtf(var + EPS);
#pragma unroll
    for (int i = 0; i < 4; ++i) {
        const int c = tid + 256 * i;
        xn[(size_t)row * D + c] = __float2bfloat16((vals[i] - mu) * rs * w[c] + b[c]);
    }
}

// ---------------------------------------------------------------------------
// bf16 MFMA GEMM, split-K, atomicAdd f32 epilogue.  BK=64, tile 64x64.
// A (bf16 activations): global_load_lds, linear dest, inverse-swizzled source.
// W (f32 weights): reg-staged float4 loads -> cvt -> swizzled ds_write_b128.
//   This folds the old convert_kernel into the GEMM (T14: loads issue before
//   the MFMA block, cvt+write after, so HBM latency hides under compute).
// LDS layout (both A and B): row r, 16B-slot s holds global k-chunk s^(r&7).
// ---------------------------------------------------------------------------
struct Segs {
    const bf16* A[5];
    const float* W[5];
    float* O[5];
    int ostride[5];
};

static __device__ inline short8 cvt8(float4 a, float4 b) {
    union { bf16 h[8]; short8 s; } u;
    u.h[0] = __float2bfloat16(a.x); u.h[1] = __float2bfloat16(a.y);
    u.h[2] = __float2bfloat16(a.z); u.h[3] = __float2bfloat16(a.w);
    u.h[4] = __float2bfloat16(b.x); u.h[5] = __float2bfloat16(b.y);
    u.h[6] = __float2bfloat16(b.z); u.h[7] = __float2bfloat16(b.w);
    return u.s;
}

__global__ __launch_bounds__(256) void gemm_bf16_sk(Segs segs, int K, int KS) {
    const int nt = blockIdx.x;
    const int seg = nt >> 4, nloc = nt & 15;
    const int m0 = blockIdx.y * 64;
    const int k0 = blockIdx.z * KS;
    const bf16* Ab = segs.A[seg];
    const float* Wb = segs.W[seg] + (size_t)(nloc * 64) * K;

    __shared__ bf16 As[2][64 * 64];
    __shared__ bf16 Bs[2][64 * 64];

    const int tid = threadIdx.x;
    const int srow = tid >> 3;                          // 0..31
    const int swz8 = ((tid & 7) ^ (srow & 7)) * 8;      // swizzled 16B slot (elems)
    // A: linear LDS dest (tid*8), inverse-swizzled global source column
    const bf16* gA = Ab + (size_t)(m0 + srow) * K + k0 + swz8;
    const size_t rowK32 = (size_t)32 * K;
    // W: linear global source column, swizzled LDS dest
    const float* gW0 = Wb + (size_t)srow * K + k0 + (tid & 7) * 8;
    const float* gW1 = gW0 + rowK32;
    const int wd0 = srow * 64 + swz8;
    const int wd1 = (srow + 32) * 64 + swz8;

    const int lane = tid & 63, wave = tid >> 6;
    const int wm = (wave >> 1) * 32, wn = (wave & 1) * 32;
    const int fr = lane & 15, kq = lane >> 4;
    const int s0 = ((kq ^ (fr & 7)) * 8);
    const int aoff = (wm + fr) * 64 + s0;
    const int boff = (wn + fr) * 64 + s0;

    f32x4 acc00 = {0.f, 0.f, 0.f, 0.f};
    f32x4 acc01 = {0.f, 0.f, 0.f, 0.f};
    f32x4 acc10 = {0.f, 0.f, 0.f, 0.f};
    f32x4 acc11 = {0.f, 0.f, 0.f, 0.f};

    const int nIter = KS >> 6;

    // prologue: stage iter 0 into buf 0
    float4 w00 = *(const float4*)(gW0);
    float4 w01 = *(const float4*)(gW0 + 4);
    float4 w10 = *(const float4*)(gW1);
    float4 w11 = *(const float4*)(gW1 + 4);
    __builtin_amdgcn_global_load_lds(AS1C(gA),          AS3(&As[0][tid * 8]),        16, 0, 0);
    __builtin_amdgcn_global_load_lds(AS1C(gA + rowK32), AS3(&As[0][2048 + tid * 8]), 16, 0, 0);
    *(short8*)&Bs[0][wd0] = cvt8(w00, w01);
    *(short8*)&Bs[0][wd1] = cvt8(w10, w11);

    int buf = 0;
    for (int it = 0; it < nIter; ++it) {
        __syncthreads();   // drains vmcnt (A) + lgkm (W writes) -> buf ready
        if (it + 1 < nIter) {
            const int ko = (it + 1) * 64;
            w00 = *(const float4*)(gW0 + ko);
            w01 = *(const float4*)(gW0 + ko + 4);
            w10 = *(const float4*)(gW1 + ko);
            w11 = *(const float4*)(gW1 + ko + 4);
            __builtin_amdgcn_global_load_lds(AS1C(gA + ko),          AS3(&As[buf ^ 1][tid * 8]),        16, 0, 0);
            __builtin_amdgcn_global_load_lds(AS1C(gA + ko + rowK32), AS3(&As[buf ^ 1][2048 + tid * 8]), 16, 0, 0);
        }
        // k-chunk 0 (k = 0..31)
        {
            const short8 a0 = *(const short8*)&As[buf][aoff];
            const short8 a1 = *(const short8*)&As[buf][aoff + 1024];
            const short8 b0 = *(const short8*)&Bs[buf][boff];
            const short8 b1 = *(const short8*)&Bs[buf][boff + 1024];
            acc00 = __builtin_amdgcn_mfma_f32_16x16x32_bf16(a0, b0, acc00, 0, 0, 0);
            acc01 = __builtin_amdgcn_mfma_f32_16x16x32_bf16(a0, b1, acc01, 0, 0, 0);
            acc10 = __builtin_amdgcn_mfma_f32_16x16x32_bf16(a1, b0, acc10, 0, 0, 0);
            acc11 = __builtin_amdgcn_mfma_f32_16x16x32_bf16(a1, b1, acc11, 0, 0, 0);
        }
        // k-chunk 1 (k = 32..63): slot ^= 4 -> element offset ^= 32
        {
            const short8 a0 = *(const short8*)&As[buf][aoff ^ 32];
            const short8 a1 = *(const short8*)&As[buf][(aoff + 1024) ^ 32];
            const short8 b0 = *(const short8*)&Bs[buf][boff ^ 32];
            const short8 b1 = *(const short8*)&Bs[buf][(boff + 1024) ^ 32];
            acc00 = __builtin_amdgcn_mfma_f32_16x16x32_bf16(a0, b0, acc00, 0, 0, 0);
            acc01 = __builtin_amdgcn_mfma_f32_16x16x32_bf16(a0, b1, acc01, 0, 0, 0);
            acc10 = __builtin_amdgcn_mfma_f32_16x16x32_bf16(a1, b0, acc10, 0, 0, 0);
            acc11 = __builtin_amdgcn_mfma_f32_16x16x32_bf16(a1, b1, acc11, 0, 0, 0);
        }
        if (it + 1 < nIter) {
            // waitcnt for w-loads lands here, after the MFMA block (hidden)
            *(short8*)&Bs[buf ^ 1][wd0] = cvt8(w00, w01);
            *(short8*)&Bs[buf ^ 1][wd1] = cvt8(w10, w11);
        }
        buf ^= 1;
    }

    float* Ob = segs.O[seg] + nloc * 64 + wn;
    const int ost = segs.ostride[seg];
    const int r0 = m0 + wm + (lane >> 4) * 4;
    const int c0 = lane & 15;
#pragma unroll
    for (int r = 0; r < 4; ++r) {
        atomicAdd(&Ob[(size_t)(r0 + r) * ost + c0],           acc00[r]);
        atomicAdd(&Ob[(size_t)(r0 + r) * ost + 16 + c0],      acc01[r]);
        atomicAdd(&Ob[(size_t)(r0 + r + 16) * ost + c0],      acc10[r]);
        atomicAdd(&Ob[(size_t)(r0 + r + 16) * ost + 16 + c0], acc11[r]);
    }
}

// ---------------------------------------------------------------------------
// Conv epilogue: x_t = xtacc + up_l_b (writes bf16 copy), causal conv K=4,
// SiLU -> x_c (f32 + bf16)
// ---------------------------------------------------------------------------
__global__ __launch_bounds__(256) void conv_kernel(
    const float* __restrict__ xtacc, const float* __restrict__ ulb,
    const float* __restrict__ cw, const float* __restrict__ cb,
    bf16* __restrict__ xt_bf, float* __restrict__ xc, bf16* __restrict__ xc_bf)
{
    const int idx = blockIdx.x * 256 + threadIdx.x;
    const int b = idx >> 11, i = idx & 2047;
    const float* row = xtacc + (size_t)b * P;
    const float x0 = row[i] + ulb[i];
    xt_bf[idx] = __float2bfloat16(x0);
    float acc = cb[0] + cw[3] * x0;
    if (i >= 1) acc = fmaf(cw[2], row[i - 1] + ulb[i - 1], acc);
    if (i >= 2) acc = fmaf(cw[1], row[i - 2] + ulb[i - 2], acc);
    if (i >= 3) acc = fmaf(cw[0], row[i - 3] + ulb[i - 3], acc);
    const float sv = acc / (1.f + expf(-acc));
    xc[idx] = sv;
    xc_bf[idx] = __float2bfloat16(sv);
}

// ---------------------------------------------------------------------------
// i_t, f_t (f32 dot products, one block per (b,h))
// ---------------------------------------------------------------------------
__global__ __launch_bounds__(256) void if_kernel(
    const float* __restrict__ xc,
    const float* __restrict__ Wi, const float* __restrict__ Wib,
    const float* __restrict__ Wf, const float* __restrict__ Wfb,
    float* __restrict__ it, float* __restrict__ ft)
{
    const int blk = blockIdx.x;
    const int b = blk >> 3, h = blk & 7;
    const int tid = threadIdx.x;
    const int lane = tid & 63, wv = tid >> 6;
    const float* x = xc + (size_t)b * P;
    const float* wi = Wi + (size_t)h * P;
    const float* wf = Wf + (size_t)h * P;
    float pi = 0.f, pf = 0.f;
    for (int p = tid; p < P; p += 256) {
        const float xv = x[p];
        pi = fmaf(xv, wi[p], pi);
        pf = fmaf(xv, wf[p], pf);
    }
    __shared__ float red[8];
#pragma unroll
    for (int off = 32; off; off >>= 1) {
        pi += __shfl_down(pi, off, 64);
        pf += __shfl_down(pf, off, 64);
    }
    if (lane == 0) { red[wv] = pi; red[4 + wv] = pf; }
    __syncthreads();
    if (tid == 0) {
        it[blk] = red[0] + red[1] + red[2] + red[3] + Wib[h];
        ft[blk] = red[4] + red[5] + red[6] + red[7] + Wfb[h];
    }
}

// ---------------------------------------------------------------------------
// Fused gate kernel v3: biases folded in; writes c_t, n_t, m_t and y (bf16).
// Phase 1: pure linear-float4 stream over c (1024B/wave-instr, fully
// coalesced); each thread owns a fixed 4-col chunk and accumulates 16
// per-row dot partials in registers -> ZERO shuffles on the stream path.
// Phase 2: one batch of 5x16 shfl_xor (32-lane groups) finishes num.
// ---------------------------------------------------------------------------
__global__ __launch_bounds__(256) void gate_kernel(
    const float* __restrict__ c_tm1, const float* __restrict__ n_tm1,
    const float* __restrict__ m_tm1, const float* __restrict__ it_a,
    const float* __restrict__ ft_a,
    const float* __restrict__ qacc, const float* __restrict__ kacc,
    const float* __restrict__ vacc, const float* __restrict__ oacc,
    const float* __restrict__ sacc, const float* __restrict__ racc,
    const float* __restrict__ qb, const float* __restrict__ kb,
    const float* __restrict__ vb, const float* __restrict__ ob,
    const float* __restrict__ rb,
    const float* __restrict__ gn_w, const float* __restrict__ gn_b,
    float* __restrict__ c_out, float* __restrict__ n_out,
    float* __restrict__ m_out, bf16* __restrict__ y)
{
    const int blk = blockIdx.x;          // b*H + h
    const int b = blk >> 3, h = blk & 7;
    const int tid = threadIdx.x;
    const int lane = tid & 63, wv = tid >> 6;
    const float kscale = 0.08838834764831845f;  // 1/sqrt(128)

    __shared__ __align__(16) float sk_[128];
    __shared__ __align__(16) float sq_[128];
    __shared__ __align__(16) float sv_[128];
    __shared__ __align__(16) float snum[128];
    __shared__ float red[8];

    const float it = it_a[blk], ft = ft_a[blk], mp = m_tm1[blk];
    const float mt = fmaxf(ft + mp, it);
    const float ig = expf(it - mt);
    const float fg = expf(ft - mt + mp);
    if (tid == 0) m_out[blk] = mt;

    const int col0 = h * HD;
    const int hid_off = b * HID + col0;
    float den_p = 0.f;
    if (tid < 128) {
        const int col = col0 + tid;
        const float kd = (kacc[hid_off + tid] + kb[col]) * kscale;
        const float qd = qacc[hid_off + tid] + qb[col];
        sk_[tid] = kd; sq_[tid] = qd;
        sv_[tid] = vacc[hid_off + tid] + vb[col];
        const float nn = fg * n_tm1[(size_t)blk * HD + tid] + ig * kd;
        n_out[(size_t)blk * HD + tid] = nn;
        den_p = nn * qd;
    }
    __syncthreads();
#pragma unroll
    for (int off = 32; off; off >>= 1) den_p += __shfl_down(den_p, off, 64);
    if (lane == 0) red[wv] = den_p;
    __syncthreads();
    const float den = fmaxf(red[0] + red[1] + red[2] + red[3], 1.0f);

    // ---- phase 1: stream c update (linear float4), per-thread partials ----
    const int cchunk = tid & 31;            // float4 col chunk (fixed per thread)
    const int a0r = tid >> 5;               // base row 0..7
    const float4 k4 = *(const float4*)&sk_[cchunk * 4];
    const float4 q4 = *(const float4*)&sq_[cchunk * 4];
    const size_t cbase = (size_t)blk * (HD * HD);
    const float4* cin4 = (const float4*)(c_tm1 + cbase);
    float4* cout4 = (float4*)(c_out + cbase);
    float part[16];
#pragma unroll
    for (int j = 0; j < 16; ++j) {
        const int m = tid + 256 * j;        // = (a0r + 8j)*32 + cchunk
        const int row = a0r + 8 * j;
        const float av = ig * sv_[row];
        float4 c4 = cin4[m];
        c4.x = fmaf(fg, c4.x, av * k4.x);
        c4.y = fmaf(fg, c4.y, av * k4.y);
        c4.z = fmaf(fg, c4.z, av * k4.z);
        c4.w = fmaf(fg, c4.w, av * k4.w);
        cout4[m] = c4;
        part[j] = c4.x * q4.x + c4.y * q4.y + c4.z * q4.z + c4.w * q4.w;
    }
    // ---- phase 2: batch reduce over the 32 threads sharing a0r ----
#pragma unroll
    for (int j = 0; j < 16; ++j) {
        float p = part[j];
        p += __shfl_xor(p, 1, 64);
        p += __shfl_xor(p, 2, 64);
        p += __shfl_xor(p, 4, 64);
        p += __shfl_xor(p, 8, 64);
        p += __shfl_xor(p, 16, 64);
        if (cchunk == j) snum[a0r + 8 * j] = p;   // static index (rule #20)
    }
    __syncthreads();

    float hval = 0.f, s1 = 0.f, s2 = 0.f;
    if (tid < 128) {
        const int col = col0 + tid;
        const float ot = 1.f / (1.f + expf(-(oacc[hid_off + tid] + ob[col])));
        hval = ot * snum[tid] / den;
        s1 = hval; s2 = hval * hval;
    }
#pragma unroll
    for (int off = 32; off; off >>= 1) {
        s1 += __shfl_down(s1, off, 64);
        s2 += __shfl_down(s2, off, 64);
    }
    if (lane == 0) { red[wv] = s1; red[4 + wv] = s2; }
    __syncthreads();
    const float mu = (red[0] + red[1] + red[2] + red[3]) * (1.f / HD);
    const float ms = (red[4] + red[5] + red[6] + red[7]) * (1.f / HD);
    const float var = ms - mu * mu;
    if (tid < 128) {
        const int col = col0 + tid;
        const float hn = (hval - mu) * rsqrtf(var + EPS) * gn_w[col] + gn_b[col];
        const float sr = racc[hid_off + tid] + rb[col];
        const float silu_r = sr / (1.f + expf(-sr));
        y[hid_off + tid] = __float2bfloat16((hn + sacc[hid_off + tid]) * silu_r);
    }
}

// ---------------------------------------------------------------------------
// Final epilogue: out = dacc + down_b + seq
// ---------------------------------------------------------------------------
__global__ __launch_bounds__(256) void e3_kernel(
    const float* __restrict__ dacc, const float* __restrict__ db,
    const float* __restrict__ seq, float* __restrict__ out)
{
    const int i = blockIdx.x * 256 + threadIdx.x;   // float4 chunks, 65536 total
    const float4 d = ((const float4*)dacc)[i];
    const float4 s = ((const float4*)seq)[i];
    const float4 bb = ((const float4*)db)[i & 255];
    float4 o;
    o.x = d.x + s.x + bb.x; o.y = d.y + s.y + bb.y;
    o.z = d.z + s.z + bb.z; o.w = d.w + s.w + bb.w;
    ((float4*)out)[i] = o;
}

// ---------------------------------------------------------------------------
extern "C" void kernel_launch(void* const* d_in, const int* in_sizes, int n_in,
                              void* d_out, int out_size, void* d_ws, size_t ws_size,
                              hipStream_t stream) {
    const float* seq    = (const float*)d_in[0];
    const float* c_tm1  = (const float*)d_in[1];
    const float* n_tm1  = (const float*)d_in[2];
    const float* m_tm1  = (const float*)d_in[3];
    const float* ln_w   = (const float*)d_in[4];
    const float* ln_b   = (const float*)d_in[5];
    const float* gn_w   = (const float*)d_in[6];
    const float* gn_b   = (const float*)d_in[7];
    const float* up_l_w = (const float*)d_in[8];
    const float* up_l_b = (const float*)d_in[9];
    const float* up_r_w = (const float*)d_in[10];
    const float* up_r_b = (const float*)d_in[11];
    const float* down_w = (const float*)d_in[12];
    const float* down_b = (const float*)d_in[13];
    const float* Wi_w   = (const float*)d_in[14];
    const float* Wi_b   = (const float*)d_in[15];
    const float* Wf_w   = (const float*)d_in[16];
    const float* Wf_b   = (const float*)d_in[17];
    const float* Wo_w   = (const float*)d_in[18];
    const float* Wo_b   = (const float*)d_in[19];
    const float* Wq_w   = (const float*)d_in[20];
    const float* Wq_b   = (const float*)d_in[21];
    const float* Wk_w   = (const float*)d_in[22];
    const float* Wk_b   = (const float*)d_in[23];
    const float* Wv_w   = (const float*)d_in[24];
    const float* Wv_b   = (const float*)d_in[25];
    const float* conv_w = (const float*)d_in[26];
    const float* conv_b = (const float*)d_in[27];
    const float* skip_w = (const float*)d_in[28];

    // --- workspace (f32 accumulators must be zeroed; ~10 MB used) ---
    float* ws = (float*)d_ws;
    float* xtacc = ws;                    // 524288
    float* racc  = ws + 524288;           // 262144
    float* qacc  = ws + 786432;
    float* kacc  = ws + 1048576;
    float* vacc  = ws + 1310720;
    float* oacc  = ws + 1572864;
    float* sacc  = ws + 1835008;
    float* dacc  = ws + 2097152;          // ends 2359296 (zero region)
    float* itb   = ws + 2359296;          // 2048
    float* ftb   = ws + 2361344;          // 2048
    bf16* yb_bf  = (bf16*)(ws + 2363392); // 262144 bf16

    // --- outputs; c_t region doubles as scratch until gate_kernel runs ---
    float* out0  = (float*)d_out;
    float* c_out = out0 + 262144;
    float* n_out = out0 + 33816576;
    float* m_out = out0 + 34078720;

    bf16* wbuf   = (bf16*)c_out;          // 128 MB of pre-gate scratch
    bf16* xn_bf  = wbuf;                  // 262144
    bf16* xt_bf  = wbuf + 262144;         // 524288
    bf16* xc_bf  = wbuf + 786432;         // 524288
    float* xc_f  = (float*)(wbuf + 1310720);  // 524288 f32 (ends bf16 2359296)

    // zero the atomic accumulators (2359296 floats = 589824 float4)
    zero_kernel<<<2304, 256, 0, stream>>>(ws);

    ln_kernel<<<B, 256, 0, stream>>>(seq, ln_w, ln_b, xn_bf);

    // GEMM1: x_n @ {up_l, up_r}^T   (K=1024, N-segments of 1024)
    Segs g1{};
    g1.A[0] = xn_bf; g1.W[0] = up_l_w;               g1.O[0] = xtacc;        g1.ostride[0] = P;
    g1.A[1] = xn_bf; g1.W[1] = up_l_w + 1024 * 1024; g1.O[1] = xtacc + 1024; g1.ostride[1] = P;
    g1.A[2] = xn_bf; g1.W[2] = up_r_w;               g1.O[2] = racc;         g1.ostride[2] = HID;
    gemm_bf16_sk<<<dim3(48, 4, 4), 256, 0, stream>>>(g1, 1024, 256);

    conv_kernel<<<(B * P) / 256, 256, 0, stream>>>(
        xtacc, up_l_b, conv_w, conv_b, xt_bf, xc_f, xc_bf);

    // GEMM2: {q,k,skip} from x_c; {v,o} from x_t  (K=2048)
    Segs g2{};
    g2.A[0] = xc_bf; g2.W[0] = Wq_w;   g2.O[0] = qacc; g2.ostride[0] = HID;
    g2.A[1] = xc_bf; g2.W[1] = Wk_w;   g2.O[1] = kacc; g2.ostride[1] = HID;
    g2.A[2] = xt_bf; g2.W[2] = Wv_w;   g2.O[2] = vacc; g2.ostride[2] = HID;
    g2.A[3] = xt_bf; g2.W[3] = Wo_w;   g2.O[3] = oacc; g2.ostride[3] = HID;
    g2.A[4] = xc_bf; g2.W[4] = skip_w; g2.O[4] = sacc; g2.ostride[4] = HID;
    gemm_bf16_sk<<<dim3(80, 4, 2), 256, 0, stream>>>(g2, 2048, 1024);

    if_kernel<<<B * H, 256, 0, stream>>>(xc_f, Wi_w, Wi_b, Wf_w, Wf_b, itb, ftb);

    gate_kernel<<<B * H, 256, 0, stream>>>(
        c_tm1, n_tm1, m_tm1, itb, ftb,
        qacc, kacc, vacc, oacc, sacc, racc,
        Wq_b, Wk_b, Wv_b, Wo_b, up_r_b, gn_w, gn_b,
        c_out, n_out, m_out, yb_bf);

    // GEMM3: y @ down^T  (K=1024)
    Segs g3{};
    g3.A[0] = yb_bf; g3.W[0] = down_w; g3.O[0] = dacc; g3.ostride[0] = HID;
    gemm_bf16_sk<<<dim3(16, 4, 4), 256, 0, stream>>>(g3, 1024, 256);

    e3_kernel<<<256, 256, 0, stream>>>(dacc, down_b, seq, out0);
}

// Round 7
// 393.010 us; speedup vs baseline: 1.0010x; 1.0010x over previous
//
#include <hip/hip_runtime.h>
#include <hip/hip_bf16.h>
#include <math.h>

#define B 256
#define D 1024
#define H 8
#define HD 128
#define P 2048
#define HID 1024
#define EPS 1e-5f

typedef __hip_bfloat16 bf16;
typedef short short8 __attribute__((ext_vector_type(8)));
typedef float f32x4 __attribute__((ext_vector_type(4)));

#define AS1C(p) ((const __attribute__((address_space(1))) void*)(p))
#define AS3(p)  ((__attribute__((address_space(3))) void*)(p))

// ---------------------------------------------------------------------------
// Zero the split-K f32 accumulators. 2359296 floats = 589824 float4.
// ---------------------------------------------------------------------------
__global__ __launch_bounds__(256) void zero_kernel(float* __restrict__ p) {
    const int i = blockIdx.x * 256 + threadIdx.x;
    ((float4*)p)[i] = float4{0.f, 0.f, 0.f, 0.f};
}

// ---------------------------------------------------------------------------
// LayerNorm -> bf16 output
// ---------------------------------------------------------------------------
__global__ __launch_bounds__(256) void ln_kernel(
    const float* __restrict__ seq, const float* __restrict__ w,
    const float* __restrict__ b, bf16* __restrict__ xn)
{
    const int row = blockIdx.x;
    const int tid = threadIdx.x;
    const int lane = tid & 63, wv = tid >> 6;
    const float* x = seq + (size_t)row * D;
    __shared__ float red[8];

    float vals[4];
    float s = 0.f, s2 = 0.f;
#pragma unroll
    for (int i = 0; i < 4; ++i) {
        float v = x[tid + 256 * i];
        vals[i] = v; s += v; s2 += v * v;
    }
#pragma unroll
    for (int off = 32; off; off >>= 1) {
        s  += __shfl_down(s, off, 64);
        s2 += __shfl_down(s2, off, 64);
    }
    if (lane == 0) { red[wv] = s; red[4 + wv] = s2; }
    __syncthreads();
    const float tot  = red[0] + red[1] + red[2] + red[3];
    const float tot2 = red[4] + red[5] + red[6] + red[7];
    const float mu = tot * (1.f / D);
    const float var = tot2 * (1.f / D) - mu * mu;
    const float rs = rsqrtf(var + EPS);
#pragma unroll
    for (int i = 0; i < 4; ++i) {
        const int c = tid + 256 * i;
        xn[(size_t)row * D + c] = __float2bfloat16((vals[i] - mu) * rs * w[c] + b[c]);
    }
}

// ---------------------------------------------------------------------------
// bf16 MFMA GEMM, split-K, atomicAdd f32 epilogue.  BK=64, tile 64x64.
// A (bf16 activations): global_load_lds, linear dest, inverse-swizzled source.
// W (f32 weights): reg-staged float4 loads -> cvt -> swizzled ds_write_b128.
// LDS layout (both A and B): row r, 16B-slot s holds global k-chunk s^(r&7).
// ---------------------------------------------------------------------------
struct Segs {
    const bf16* A[5];
    const float* W[5];
    float* O[5];
    int ostride[5];
};

static __device__ inline short8 cvt8(float4 a, float4 b) {
    union { bf16 h[8]; short8 s; } u;
    u.h[0] = __float2bfloat16(a.x); u.h[1] = __float2bfloat16(a.y);
    u.h[2] = __float2bfloat16(a.z); u.h[3] = __float2bfloat16(a.w);
    u.h[4] = __float2bfloat16(b.x); u.h[5] = __float2bfloat16(b.y);
    u.h[6] = __float2bfloat16(b.z); u.h[7] = __float2bfloat16(b.w);
    return u.s;
}

__global__ __launch_bounds__(256) void gemm_bf16_sk(Segs segs, int K, int KS) {
    const int nt = blockIdx.x;
    const int seg = nt >> 4, nloc = nt & 15;
    const int m0 = blockIdx.y * 64;
    const int k0 = blockIdx.z * KS;
    const bf16* Ab = segs.A[seg];
    const float* Wb = segs.W[seg] + (size_t)(nloc * 64) * K;

    __shared__ bf16 As[2][64 * 64];
    __shared__ bf16 Bs[2][64 * 64];

    const int tid = threadIdx.x;
    const int srow = tid >> 3;                          // 0..31
    const int swz8 = ((tid & 7) ^ (srow & 7)) * 8;      // swizzled 16B slot (elems)
    const bf16* gA = Ab + (size_t)(m0 + srow) * K + k0 + swz8;
    const size_t rowK32 = (size_t)32 * K;
    const float* gW0 = Wb + (size_t)srow * K + k0 + (tid & 7) * 8;
    const float* gW1 = gW0 + rowK32;
    const int wd0 = srow * 64 + swz8;
    const int wd1 = (srow + 32) * 64 + swz8;

    const int lane = tid & 63, wave = tid >> 6;
    const int wm = (wave >> 1) * 32, wn = (wave & 1) * 32;
    const int fr = lane & 15, kq = lane >> 4;
    const int s0 = ((kq ^ (fr & 7)) * 8);
    const int aoff = (wm + fr) * 64 + s0;
    const int boff = (wn + fr) * 64 + s0;

    f32x4 acc00 = {0.f, 0.f, 0.f, 0.f};
    f32x4 acc01 = {0.f, 0.f, 0.f, 0.f};
    f32x4 acc10 = {0.f, 0.f, 0.f, 0.f};
    f32x4 acc11 = {0.f, 0.f, 0.f, 0.f};

    const int nIter = KS >> 6;

    float4 w00 = *(const float4*)(gW0);
    float4 w01 = *(const float4*)(gW0 + 4);
    float4 w10 = *(const float4*)(gW1);
    float4 w11 = *(const float4*)(gW1 + 4);
    __builtin_amdgcn_global_load_lds(AS1C(gA),          AS3(&As[0][tid * 8]),        16, 0, 0);
    __builtin_amdgcn_global_load_lds(AS1C(gA + rowK32), AS3(&As[0][2048 + tid * 8]), 16, 0, 0);
    *(short8*)&Bs[0][wd0] = cvt8(w00, w01);
    *(short8*)&Bs[0][wd1] = cvt8(w10, w11);

    int buf = 0;
    for (int it = 0; it < nIter; ++it) {
        __syncthreads();
        if (it + 1 < nIter) {
            const int ko = (it + 1) * 64;
            w00 = *(const float4*)(gW0 + ko);
            w01 = *(const float4*)(gW0 + ko + 4);
            w10 = *(const float4*)(gW1 + ko);
            w11 = *(const float4*)(gW1 + ko + 4);
            __builtin_amdgcn_global_load_lds(AS1C(gA + ko),          AS3(&As[buf ^ 1][tid * 8]),        16, 0, 0);
            __builtin_amdgcn_global_load_lds(AS1C(gA + ko + rowK32), AS3(&As[buf ^ 1][2048 + tid * 8]), 16, 0, 0);
        }
        {
            const short8 a0 = *(const short8*)&As[buf][aoff];
            const short8 a1 = *(const short8*)&As[buf][aoff + 1024];
            const short8 b0 = *(const short8*)&Bs[buf][boff];
            const short8 b1 = *(const short8*)&Bs[buf][boff + 1024];
            acc00 = __builtin_amdgcn_mfma_f32_16x16x32_bf16(a0, b0, acc00, 0, 0, 0);
            acc01 = __builtin_amdgcn_mfma_f32_16x16x32_bf16(a0, b1, acc01, 0, 0, 0);
            acc10 = __builtin_amdgcn_mfma_f32_16x16x32_bf16(a1, b0, acc10, 0, 0, 0);
            acc11 = __builtin_amdgcn_mfma_f32_16x16x32_bf16(a1, b1, acc11, 0, 0, 0);
        }
        {
            const short8 a0 = *(const short8*)&As[buf][aoff ^ 32];
            const short8 a1 = *(const short8*)&As[buf][(aoff + 1024) ^ 32];
            const short8 b0 = *(const short8*)&Bs[buf][boff ^ 32];
            const short8 b1 = *(const short8*)&Bs[buf][(boff + 1024) ^ 32];
            acc00 = __builtin_amdgcn_mfma_f32_16x16x32_bf16(a0, b0, acc00, 0, 0, 0);
            acc01 = __builtin_amdgcn_mfma_f32_16x16x32_bf16(a0, b1, acc01, 0, 0, 0);
            acc10 = __builtin_amdgcn_mfma_f32_16x16x32_bf16(a1, b0, acc10, 0, 0, 0);
            acc11 = __builtin_amdgcn_mfma_f32_16x16x32_bf16(a1, b1, acc11, 0, 0, 0);
        }
        if (it + 1 < nIter) {
            *(short8*)&Bs[buf ^ 1][wd0] = cvt8(w00, w01);
            *(short8*)&Bs[buf ^ 1][wd1] = cvt8(w10, w11);
        }
        buf ^= 1;
    }

    float* Ob = segs.O[seg] + nloc * 64 + wn;
    const int ost = segs.ostride[seg];
    const int r0 = m0 + wm + (lane >> 4) * 4;
    const int c0 = lane & 15;
#pragma unroll
    for (int r = 0; r < 4; ++r) {
        atomicAdd(&Ob[(size_t)(r0 + r) * ost + c0],           acc00[r]);
        atomicAdd(&Ob[(size_t)(r0 + r) * ost + 16 + c0],      acc01[r]);
        atomicAdd(&Ob[(size_t)(r0 + r + 16) * ost + c0],      acc10[r]);
        atomicAdd(&Ob[(size_t)(r0 + r + 16) * ost + 16 + c0], acc11[r]);
    }
}

// ---------------------------------------------------------------------------
// Conv epilogue
// ---------------------------------------------------------------------------
__global__ __launch_bounds__(256) void conv_kernel(
    const float* __restrict__ xtacc, const float* __restrict__ ulb,
    const float* __restrict__ cw, const float* __restrict__ cb,
    bf16* __restrict__ xt_bf, float* __restrict__ xc, bf16* __restrict__ xc_bf)
{
    const int idx = blockIdx.x * 256 + threadIdx.x;
    const int b = idx >> 11, i = idx & 2047;
    const float* row = xtacc + (size_t)b * P;
    const float x0 = row[i] + ulb[i];
    xt_bf[idx] = __float2bfloat16(x0);
    float acc = cb[0] + cw[3] * x0;
    if (i >= 1) acc = fmaf(cw[2], row[i - 1] + ulb[i - 1], acc);
    if (i >= 2) acc = fmaf(cw[1], row[i - 2] + ulb[i - 2], acc);
    if (i >= 3) acc = fmaf(cw[0], row[i - 3] + ulb[i - 3], acc);
    const float sv = acc / (1.f + expf(-acc));
    xc[idx] = sv;
    xc_bf[idx] = __float2bfloat16(sv);
}

// ---------------------------------------------------------------------------
// i_t, f_t (f32 dot products, one block per (b,h))
// ---------------------------------------------------------------------------
__global__ __launch_bounds__(256) void if_kernel(
    const float* __restrict__ xc,
    const float* __restrict__ Wi, const float* __restrict__ Wib,
    const float* __restrict__ Wf, const float* __restrict__ Wfb,
    float* __restrict__ it, float* __restrict__ ft)
{
    const int blk = blockIdx.x;
    const int b = blk >> 3, h = blk & 7;
    const int tid = threadIdx.x;
    const int lane = tid & 63, wv = tid >> 6;
    const float* x = xc + (size_t)b * P;
    const float* wi = Wi + (size_t)h * P;
    const float* wf = Wf + (size_t)h * P;
    float pi = 0.f, pf = 0.f;
    for (int p = tid; p < P; p += 256) {
        const float xv = x[p];
        pi = fmaf(xv, wi[p], pi);
        pf = fmaf(xv, wf[p], pf);
    }
    __shared__ float red[8];
#pragma unroll
    for (int off = 32; off; off >>= 1) {
        pi += __shfl_down(pi, off, 64);
        pf += __shfl_down(pf, off, 64);
    }
    if (lane == 0) { red[wv] = pi; red[4 + wv] = pf; }
    __syncthreads();
    if (tid == 0) {
        it[blk] = red[0] + red[1] + red[2] + red[3] + Wib[h];
        ft[blk] = red[4] + red[5] + red[6] + red[7] + Wfb[h];
    }
}

// ---------------------------------------------------------------------------
// Fused gate kernel v4b.  Latency fix for the c-stream: loads batched
// 8x float4 into registers BEFORE compute+store (8KB/wave in flight vs the
// ~2-3 the 48-VGPR v3 allowed -> Little's law satisfied at ~20 waves/CU).
// Plain stores (NT-store variant deferred: isolate one lever per round).
// ---------------------------------------------------------------------------
__global__ __launch_bounds__(256) void gate_kernel(
    const float* __restrict__ c_tm1, const float* __restrict__ n_tm1,
    const float* __restrict__ m_tm1, const float* __restrict__ it_a,
    const float* __restrict__ ft_a,
    const float* __restrict__ qacc, const float* __restrict__ kacc,
    const float* __restrict__ vacc, const float* __restrict__ oacc,
    const float* __restrict__ sacc, const float* __restrict__ racc,
    const float* __restrict__ qb, const float* __restrict__ kb,
    const float* __restrict__ vb, const float* __restrict__ ob,
    const float* __restrict__ rb,
    const float* __restrict__ gn_w, const float* __restrict__ gn_b,
    float* __restrict__ c_out, float* __restrict__ n_out,
    float* __restrict__ m_out, bf16* __restrict__ y)
{
    const int blk = blockIdx.x;          // b*H + h
    const int b = blk >> 3, h = blk & 7;
    const int tid = threadIdx.x;
    const int lane = tid & 63, wv = tid >> 6;
    const float kscale = 0.08838834764831845f;  // 1/sqrt(128)

    __shared__ __align__(16) float sk_[128];
    __shared__ __align__(16) float sq_[128];
    __shared__ __align__(16) float sv_[128];
    __shared__ __align__(16) float snum[128];
    __shared__ float red[8];

    const float it = it_a[blk], ft = ft_a[blk], mp = m_tm1[blk];
    const float mt = fmaxf(ft + mp, it);
    const float ig = expf(it - mt);
    const float fg = expf(ft - mt + mp);
    if (tid == 0) m_out[blk] = mt;

    const int col0 = h * HD;
    const int hid_off = b * HID + col0;
    float den_p = 0.f;
    if (tid < 128) {
        const int col = col0 + tid;
        const float kd = (kacc[hid_off + tid] + kb[col]) * kscale;
        const float qd = qacc[hid_off + tid] + qb[col];
        sk_[tid] = kd; sq_[tid] = qd;
        sv_[tid] = vacc[hid_off + tid] + vb[col];
        const float nn = fg * n_tm1[(size_t)blk * HD + tid] + ig * kd;
        n_out[(size_t)blk * HD + tid] = nn;
        den_p = nn * qd;
    }
    __syncthreads();
#pragma unroll
    for (int off = 32; off; off >>= 1) den_p += __shfl_down(den_p, off, 64);
    if (lane == 0) red[wv] = den_p;
    __syncthreads();
    const float den = fmaxf(red[0] + red[1] + red[2] + red[3], 1.0f);

    // ---- phase 1: stream c update, 8-deep load batches ----
    const int cchunk = tid & 31;            // float4 col chunk (fixed per thread)
    const int a0r = tid >> 5;               // base row 0..7
    const float4 k4 = *(const float4*)&sk_[cchunk * 4];
    const float4 q4 = *(const float4*)&sq_[cchunk * 4];
    const size_t cbase = (size_t)blk * (HD * HD);
    const float4* cin4 = (const float4*)(c_tm1 + cbase);
    float4* cout4 = (float4*)(c_out + cbase);
    float part[16];
#pragma unroll
    for (int pass = 0; pass < 2; ++pass) {
        float4 cc[8];
#pragma unroll
        for (int j = 0; j < 8; ++j)
            cc[j] = cin4[tid + 256 * (pass * 8 + j)];
#pragma unroll
        for (int j = 0; j < 8; ++j) {
            const int jj = pass * 8 + j;
            const int row = a0r + 8 * jj;
            const float av = ig * sv_[row];
            float4 c4 = cc[j];
            c4.x = fmaf(fg, c4.x, av * k4.x);
            c4.y = fmaf(fg, c4.y, av * k4.y);
            c4.z = fmaf(fg, c4.z, av * k4.z);
            c4.w = fmaf(fg, c4.w, av * k4.w);
            cout4[tid + 256 * jj] = c4;
            part[jj] = c4.x * q4.x + c4.y * q4.y + c4.z * q4.z + c4.w * q4.w;
        }
    }
    // ---- phase 2: batch reduce over the 32 threads sharing a0r ----
#pragma unroll
    for (int j = 0; j < 16; ++j) {
        float p = part[j];
        p += __shfl_xor(p, 1, 64);
        p += __shfl_xor(p, 2, 64);
        p += __shfl_xor(p, 4, 64);
        p += __shfl_xor(p, 8, 64);
        p += __shfl_xor(p, 16, 64);
        if (cchunk == j) snum[a0r + 8 * j] = p;   // static index (rule #20)
    }
    __syncthreads();

    float hval = 0.f, s1 = 0.f, s2 = 0.f;
    if (tid < 128) {
        const int col = col0 + tid;
        const float ot = 1.f / (1.f + expf(-(oacc[hid_off + tid] + ob[col])));
        hval = ot * snum[tid] / den;
        s1 = hval; s2 = hval * hval;
    }
#pragma unroll
    for (int off = 32; off; off >>= 1) {
        s1 += __shfl_down(s1, off, 64);
        s2 += __shfl_down(s2, off, 64);
    }
    if (lane == 0) { red[wv] = s1; red[4 + wv] = s2; }
    __syncthreads();
    const float mu = (red[0] + red[1] + red[2] + red[3]) * (1.f / HD);
    const float ms = (red[4] + red[5] + red[6] + red[7]) * (1.f / HD);
    const float var = ms - mu * mu;
    if (tid < 128) {
        const int col = col0 + tid;
        const float hn = (hval - mu) * rsqrtf(var + EPS) * gn_w[col] + gn_b[col];
        const float sr = racc[hid_off + tid] + rb[col];
        const float silu_r = sr / (1.f + expf(-sr));
        y[hid_off + tid] = __float2bfloat16((hn + sacc[hid_off + tid]) * silu_r);
    }
}

// ---------------------------------------------------------------------------
// Final epilogue: out = dacc + down_b + seq
// ---------------------------------------------------------------------------
__global__ __launch_bounds__(256) void e3_kernel(
    const float* __restrict__ dacc, const float* __restrict__ db,
    const float* __restrict__ seq, float* __restrict__ out)
{
    const int i = blockIdx.x * 256 + threadIdx.x;   // float4 chunks, 65536 total
    const float4 d = ((const float4*)dacc)[i];
    const float4 s = ((const float4*)seq)[i];
    const float4 bb = ((const float4*)db)[i & 255];
    float4 o;
    o.x = d.x + s.x + bb.x; o.y = d.y + s.y + bb.y;
    o.z = d.z + s.z + bb.z; o.w = d.w + s.w + bb.w;
    ((float4*)out)[i] = o;
}

// ---------------------------------------------------------------------------
extern "C" void kernel_launch(void* const* d_in, const int* in_sizes, int n_in,
                              void* d_out, int out_size, void* d_ws, size_t ws_size,
                              hipStream_t stream) {
    const float* seq    = (const float*)d_in[0];
    const float* c_tm1  = (const float*)d_in[1];
    const float* n_tm1  = (const float*)d_in[2];
    const float* m_tm1  = (const float*)d_in[3];
    const float* ln_w   = (const float*)d_in[4];
    const float* ln_b   = (const float*)d_in[5];
    const float* gn_w   = (const float*)d_in[6];
    const float* gn_b   = (const float*)d_in[7];
    const float* up_l_w = (const float*)d_in[8];
    const float* up_l_b = (const float*)d_in[9];
    const float* up_r_w = (const float*)d_in[10];
    const float* up_r_b = (const float*)d_in[11];
    const float* down_w = (const float*)d_in[12];
    const float* down_b = (const float*)d_in[13];
    const float* Wi_w   = (const float*)d_in[14];
    const float* Wi_b   = (const float*)d_in[15];
    const float* Wf_w   = (const float*)d_in[16];
    const float* Wf_b   = (const float*)d_in[17];
    const float* Wo_w   = (const float*)d_in[18];
    const float* Wo_b   = (const float*)d_in[19];
    const float* Wq_w   = (const float*)d_in[20];
    const float* Wq_b   = (const float*)d_in[21];
    const float* Wk_w   = (const float*)d_in[22];
    const float* Wk_b   = (const float*)d_in[23];
    const float* Wv_w   = (const float*)d_in[24];
    const float* Wv_b   = (const float*)d_in[25];
    const float* conv_w = (const float*)d_in[26];
    const float* conv_b = (const float*)d_in[27];
    const float* skip_w = (const float*)d_in[28];

    // --- workspace (f32 accumulators must be zeroed; ~10 MB used) ---
    float* ws = (float*)d_ws;
    float* xtacc = ws;                    // 524288
    float* racc  = ws + 524288;           // 262144
    float* qacc  = ws + 786432;
    float* kacc  = ws + 1048576;
    float* vacc  = ws + 1310720;
    float* oacc  = ws + 1572864;
    float* sacc  = ws + 1835008;
    float* dacc  = ws + 2097152;          // ends 2359296 (zero region)
    float* itb   = ws + 2359296;          // 2048
    float* ftb   = ws + 2361344;          // 2048
    bf16* yb_bf  = (bf16*)(ws + 2363392); // 262144 bf16

    // --- outputs; c_t region doubles as scratch until gate_kernel runs ---
    float* out0  = (float*)d_out;
    float* c_out = out0 + 262144;
    float* n_out = out0 + 33816576;
    float* m_out = out0 + 34078720;

    bf16* wbuf   = (bf16*)c_out;          // 128 MB of pre-gate scratch
    bf16* xn_bf  = wbuf;                  // 262144
    bf16* xt_bf  = wbuf + 262144;         // 524288
    bf16* xc_bf  = wbuf + 786432;         // 524288
    float* xc_f  = (float*)(wbuf + 1310720);  // 524288 f32 (ends bf16 2359296)

    // zero the atomic accumulators (2359296 floats = 589824 float4)
    zero_kernel<<<2304, 256, 0, stream>>>(ws);

    ln_kernel<<<B, 256, 0, stream>>>(seq, ln_w, ln_b, xn_bf);

    // GEMM1: x_n @ {up_l, up_r}^T   (K=1024, N-segments of 1024)
    Segs g1{};
    g1.A[0] = xn_bf; g1.W[0] = up_l_w;               g1.O[0] = xtacc;        g1.ostride[0] = P;
    g1.A[1] = xn_bf; g1.W[1] = up_l_w + 1024 * 1024; g1.O[1] = xtacc + 1024; g1.ostride[1] = P;
    g1.A[2] = xn_bf; g1.W[2] = up_r_w;               g1.O[2] = racc;         g1.ostride[2] = HID;
    gemm_bf16_sk<<<dim3(48, 4, 4), 256, 0, stream>>>(g1, 1024, 256);

    conv_kernel<<<(B * P) / 256, 256, 0, stream>>>(
        xtacc, up_l_b, conv_w, conv_b, xt_bf, xc_f, xc_bf);

    // GEMM2: {q,k,skip} from x_c; {v,o} from x_t  (K=2048)
    Segs g2{};
    g2.A[0] = xc_bf; g2.W[0] = Wq_w;   g2.O[0] = qacc; g2.ostride[0] = HID;
    g2.A[1] = xc_bf; g2.W[1] = Wk_w;   g2.O[1] = kacc; g2.ostride[1] = HID;
    g2.A[2] = xt_bf; g2.W[2] = Wv_w;   g2.O[2] = vacc; g2.ostride[2] = HID;
    g2.A[3] = xt_bf; g2.W[3] = Wo_w;   g2.O[3] = oacc; g2.ostride[3] = HID;
    g2.A[4] = xc_bf; g2.W[4] = skip_w; g2.O[4] = sacc; g2.ostride[4] = HID;
    gemm_bf16_sk<<<dim3(80, 4, 2), 256, 0, stream>>>(g2, 2048, 1024);

    if_kernel<<<B * H, 256, 0, stream>>>(xc_f, Wi_w, Wi_b, Wf_w, Wf_b, itb, ftb);

    gate_kernel<<<B * H, 256, 0, stream>>>(
        c_tm1, n_tm1, m_tm1, itb, ftb,
        qacc, kacc, vacc, oacc, sacc, racc,
        Wq_b, Wk_b, Wv_b, Wo_b, up_r_b, gn_w, gn_b,
        c_out, n_out, m_out, yb_bf);

    // GEMM3: y @ down^T  (K=1024)
    Segs g3{};
    g3.A[0] = yb_bf; g3.W[0] = down_w; g3.O[0] = dacc; g3.ostride[0] = HID;
    gemm_bf16_sk<<<dim3(16, 4, 4), 256, 0, stream>>>(g3, 1024, 256);

    e3_kernel<<<256, 256, 0, stream>>>(dacc, down_b, seq, out0);
}